// Round 9
// baseline (111.067 us; speedup 1.0000x reference)
//
#include <hip/hip_runtime.h>
#include <hip/hip_bf16.h>

#define F 64
#define R 64
#define O 64

typedef short bf16x8 __attribute__((ext_vector_type(8)));
typedef float f32x4 __attribute__((ext_vector_type(4)));
typedef float f32x2 __attribute__((ext_vector_type(2)));

static __device__ __forceinline__ unsigned short f2bf(float f) {
    unsigned u = __builtin_bit_cast(unsigned, f);
    unsigned r = (u + 0x7fffu + ((u >> 16) & 1u)) >> 16;
    return (unsigned short)r;
}

// ---------------------------------------------------------------------------
// Prep kernel (flat, 146 blocks x 256) — unchanged proven variant.
//   threads [0, 33280): pack W (fp32) -> Wpk (bf16, MFMA B-fragment order):
//     dst bf16x8 idx = ((nt*65 + f)*2 + kk)*64 + lane
//     elem j = W[o][f*64 + r], o = nt*16+(lane&15), r = (lane>>4)*8 + j + kk*32
//   threads [33280, 37376): prm[u] = {s, mn*s, t, c}, u = f*64 + r
// ---------------------------------------------------------------------------
__global__ __launch_bounds__(256) void fq_prep(
        const float* __restrict__ tt, const float* __restrict__ mean,
        const float* __restrict__ std_, const float* __restrict__ W,
        float* __restrict__ prm, unsigned short* __restrict__ Wpk)
{
    const int tg = blockIdx.x * 256 + threadIdx.x;
    if (tg < 65 * 512) {
        const int f    = tg >> 9;
        const int u8   = tg & 511;
        const int lane = u8 & 63;
        const int kk   = (u8 >> 6) & 1;
        const int nt   = u8 >> 7;
        const int o    = nt * 16 + (lane & 15);
        const int rb   = ((lane >> 4) << 3) + kk * 32;
        const float* src = W + o * 4160 + f * 64 + rb;
        unsigned short v[8];
#pragma unroll
        for (int j = 0; j < 8; ++j) v[j] = f2bf(src[j]);
        const int dst = ((nt * 65 + f) * 2 + kk) * 64 + lane;
        *(bf16x8*)(Wpk + (size_t)dst * 8) = *(bf16x8*)v;
    } else if (tg < 65 * 512 + 4096) {
        const int u = tg - 65 * 512;
        float sd = std_[u];
        float mn = mean[u];
        float th = tanhf(tt[u]);
        float s  = 1.2011224087864498f / sd;  // sqrt(log2(e)) / std
        float4 p;
        p.x = s;
        p.y = mn * s;
        p.z = th;
        p.w = 0.5f * (1.0f - th);
        ((float4*)prm)[u] = p;
    }
}

// ---------------------------------------------------------------------------
// Main fused kernel, V9 (cross-tile software pipeline): 256 blocks x 512 thr,
// 128 rows (2 tiles of 64) per block, 1 block/CU. Stage 1 (VALU+trans-bound)
// and stage 2 (L1-BW+MFMA-bound) sit on DIFFERENT pipes; all prior versions
// ran them sequentially and in cross-block lockstep. Here the T0-GEMM loop is
// fused with T1's stage-1 f-steps (2 per iteration), so the pipes overlap
// inside one instruction stream. Phases: A = s1(T0); B = fused {s2(T0) +
// s1(T1)}; C = s2(T1). Single xt/fireb/rinv buffer set, 3 barriers.
// ---------------------------------------------------------------------------
__global__ __launch_bounds__(512, 2) void fq_main(
        const float* __restrict__ X,
        const float4* __restrict__ prm,
        const bf16x8* __restrict__ Wp,
        float* __restrict__ out)
{
    __shared__ __align__(16) float xt[64][68];              // [f][row-in-tile]
    __shared__ __align__(16) unsigned short fireb[64][72];  // [row-in-tile][r]
    __shared__ __align__(16) float rinv[64];

    const int t    = threadIdx.x;
    const int lane = t & 63;
    const int w    = __builtin_amdgcn_readfirstlane(t >> 6);  // wave 0..7
    const int b0   = blockIdx.x * 128;   // T0: b0..b0+63, T1: b0+64..b0+127
    const int nt   = w >> 1;
    const int g    = w & 1;

    const int xrow = t >> 4;          // 0..31
    const int xf4  = (t & 15) * 4;

    // ---- early: X loads for T0 transpose + W prefetch pair (f=0,1) ---------
    float4 xh0 = *(const float4*)(X + (size_t)(b0 + xrow) * 64 + xf4);
    float4 xh1 = *(const float4*)(X + (size_t)(b0 + xrow + 32) * 64 + xf4);

    const bf16x8* wpb = Wp + (size_t)(nt * 130) * 64 + lane;
    bf16x8 pe0 = wpb[0 * 64],  pe1 = wpb[1 * 64];
    bf16x8 po0 = wpb[2 * 64],  po1 = wpb[3 * 64];

    const int m_in = lane & 15;
    const int quad = lane >> 4;
    const int q16  = quad * 16;
    const f32x4 z4 = (f32x4){0.f, 0.f, 0.f, 0.f};

    // ======================= phase A: stage 1 (T0) ==========================
    {
        f32x2 fire2[4];
#pragma unroll
        for (int i = 0; i < 4; ++i) fire2[i] = (f32x2){1.f, 1.f};
        const float* Xw = X + (size_t)(b0 + 8 * w) * 64;
        float4 p = prm[lane];
#pragma unroll 2
        for (int f = 0; f < F; ++f) {
            const int pf = (f + 1 < 64) ? f + 1 : 63;
            float4 pn = prm[pf * 64 + lane];
            f32x2 t2 = (f32x2){p.z, p.z};
            f32x2 c2 = (f32x2){p.w, p.w};
#pragma unroll
            for (int i = 0; i < 4; ++i) {
                float x0 = Xw[(2 * i) * 64 + f];
                float x1 = Xw[(2 * i + 1) * 64 + f];
                f32x2 z;
                z.x = __builtin_fmaf(x0, p.x, -p.y);
                z.y = __builtin_fmaf(x1, p.x, -p.y);
                f32x2 nz = -(z * z);
                f32x2 g2;
                g2.x = __builtin_amdgcn_exp2f(nz.x);
                g2.y = __builtin_amdgcn_exp2f(nz.y);
                fire2[i] *= g2 * t2 + c2;
            }
            p = pn;
        }
        xt[xf4 + 0][xrow] = xh0.x;  xt[xf4 + 0][xrow + 32] = xh1.x;
        xt[xf4 + 1][xrow] = xh0.y;  xt[xf4 + 1][xrow + 32] = xh1.y;
        xt[xf4 + 2][xrow] = xh0.z;  xt[xf4 + 2][xrow + 32] = xh1.z;
        xt[xf4 + 3][xrow] = xh0.w;  xt[xf4 + 3][xrow + 32] = xh1.w;
        const int r0 = 8 * w;
#pragma unroll
        for (int i = 0; i < 4; ++i) {
            fireb[r0 + 2 * i][lane]     = f2bf(fire2[i].x);
            fireb[r0 + 2 * i + 1][lane] = f2bf(fire2[i].y);
        }
#pragma unroll
        for (int i = 0; i < 4; ++i) {
            float sx = fire2[i].x, sy = fire2[i].y;
#pragma unroll
            for (int d = 1; d < 64; d <<= 1) {
                sx += __shfl_xor(sx, d);
                sy += __shfl_xor(sy, d);
            }
            if (lane == 0) {
                rinv[r0 + 2 * i]     = 1.0f / sx;
                rinv[r0 + 2 * i + 1] = 1.0f / sy;
            }
        }
    }
    __syncthreads();   // B1: xt/fireb/rinv (T0) ready

    // ============== phase B: fused { s2(T0) + s1(T1) } ======================
    bf16x8 wfrag[2][2];
#pragma unroll
    for (int mm = 0; mm < 2; ++mm) {
        const int myrow = 32 * g + 16 * mm + m_in;
        wfrag[mm][0] = *(const bf16x8*)((const char*)&fireb[myrow][0] + q16);
        wfrag[mm][1] = *(const bf16x8*)((const char*)&fireb[myrow][32] + q16);
    }

    f32x4 acc[2];
    acc[0] = z4;  acc[1] = z4;

    // stage-1(T1) state
    f32x2 fireB[4];
#pragma unroll
    for (int i = 0; i < 4; ++i) fireB[i] = (f32x2){1.f, 1.f};
    const float* Xw1 = X + (size_t)(b0 + 64 + 8 * w) * 64;
    float4 pa = prm[lane];         // f = 0
    float4 pb = prm[64 + lane];    // f = 1

#pragma unroll 1
    for (int i = 0; i < 32; ++i) {
        const int fe = 2 * i, fo = 2 * i + 1;
        bf16x8 ce0 = pe0, ce1 = pe1, co0 = po0, co1 = po1;
        const int se = (fe + 2 <= 64) ? fe + 2 : 64;   // clamp to bias slab
        const int so = (fo + 2 <= 64) ? fo + 2 : 64;
        pe0 = wpb[(2 * se) * 64];  pe1 = wpb[(2 * se + 1) * 64];
        po0 = wpb[(2 * so) * 64];  po1 = wpb[(2 * so + 1) * 64];

        // prm dist-1-iter prefetch for s1(T1)
        const int f2 = (2 * i + 2 < 64) ? 2 * i + 2 : 62;
        float4 pa2 = prm[f2 * 64 + lane];
        float4 pb2 = prm[(f2 + 1) * 64 + lane];

        // ---- s2(T0), even f ----
#pragma unroll
        for (int mm = 0; mm < 2; ++mm) {
            f32x4 U = __builtin_amdgcn_mfma_f32_16x16x32_bf16(wfrag[mm][0], ce0, z4, 0, 0, 0);
            U = __builtin_amdgcn_mfma_f32_16x16x32_bf16(wfrag[mm][1], ce1, U, 0, 0, 0);
            f32x4 xv = *(const f32x4*)&xt[fe][32 * g + 16 * mm + quad * 4];
#pragma unroll
            for (int reg = 0; reg < 4; ++reg)
                acc[mm][reg] = __builtin_fmaf(xv[reg], U[reg], acc[mm][reg]);
        }
        // ---- s1(T1), f = 2i ----
        {
            f32x2 t2 = (f32x2){pa.z, pa.z};
            f32x2 c2 = (f32x2){pa.w, pa.w};
#pragma unroll
            for (int ii = 0; ii < 4; ++ii) {
                float x0 = Xw1[(2 * ii) * 64 + fe];
                float x1 = Xw1[(2 * ii + 1) * 64 + fe];
                f32x2 z;
                z.x = __builtin_fmaf(x0, pa.x, -pa.y);
                z.y = __builtin_fmaf(x1, pa.x, -pa.y);
                f32x2 nz = -(z * z);
                f32x2 g2;
                g2.x = __builtin_amdgcn_exp2f(nz.x);
                g2.y = __builtin_amdgcn_exp2f(nz.y);
                fireB[ii] *= g2 * t2 + c2;
            }
        }
        // ---- s2(T0), odd f ----
#pragma unroll
        for (int mm = 0; mm < 2; ++mm) {
            f32x4 U = __builtin_amdgcn_mfma_f32_16x16x32_bf16(wfrag[mm][0], co0, z4, 0, 0, 0);
            U = __builtin_amdgcn_mfma_f32_16x16x32_bf16(wfrag[mm][1], co1, U, 0, 0, 0);
            f32x4 xv = *(const f32x4*)&xt[fo][32 * g + 16 * mm + quad * 4];
#pragma unroll
            for (int reg = 0; reg < 4; ++reg)
                acc[mm][reg] = __builtin_fmaf(xv[reg], U[reg], acc[mm][reg]);
        }
        // ---- s1(T1), f = 2i+1 ----
        {
            f32x2 t2 = (f32x2){pb.z, pb.z};
            f32x2 c2 = (f32x2){pb.w, pb.w};
#pragma unroll
            for (int ii = 0; ii < 4; ++ii) {
                float x0 = Xw1[(2 * ii) * 64 + fo];
                float x1 = Xw1[(2 * ii + 1) * 64 + fo];
                f32x2 z;
                z.x = __builtin_fmaf(x0, pb.x, -pb.y);
                z.y = __builtin_fmaf(x1, pb.x, -pb.y);
                f32x2 nz = -(z * z);
                f32x2 g2;
                g2.x = __builtin_amdgcn_exp2f(nz.x);
                g2.y = __builtin_amdgcn_exp2f(nz.y);
                fireB[ii] *= g2 * t2 + c2;
            }
        }
        pa = pa2;  pb = pb2;
    }

    // bias slab (T0): pair resident in pe0/pe1 from the exit prefetch
#pragma unroll
    for (int mm = 0; mm < 2; ++mm) {
        f32x4 U = __builtin_amdgcn_mfma_f32_16x16x32_bf16(wfrag[mm][0], pe0, z4, 0, 0, 0);
        U = __builtin_amdgcn_mfma_f32_16x16x32_bf16(wfrag[mm][1], pe1, U, 0, 0, 0);
#pragma unroll
        for (int reg = 0; reg < 4; ++reg)
            acc[mm][reg] += U[reg];
    }
    // store out(T0) — reads rinv(T0) BEFORE barrier B2
#pragma unroll
    for (int mm = 0; mm < 2; ++mm) {
        f32x4 rv = *(const f32x4*)&rinv[32 * g + 16 * mm + quad * 4];
#pragma unroll
        for (int reg = 0; reg < 4; ++reg) {
            const int row = b0 + 32 * g + 16 * mm + quad * 4 + reg;
            out[(size_t)row * 64 + nt * 16 + m_in] = acc[mm][reg] * rv[reg];
        }
    }

    // X loads for T1 transpose + re-issue W f=0,1 prefetch for phase C
    float4 yh0 = *(const float4*)(X + (size_t)(b0 + 64 + xrow) * 64 + xf4);
    float4 yh1 = *(const float4*)(X + (size_t)(b0 + 96 + xrow) * 64 + xf4);
    pe0 = wpb[0 * 64];  pe1 = wpb[1 * 64];
    po0 = wpb[2 * 64];  po1 = wpb[3 * 64];

    __syncthreads();   // B2: all reads of xt/fireb/rinv (T0) complete

    // write xt/fireb/rinv for T1
    {
        xt[xf4 + 0][xrow] = yh0.x;  xt[xf4 + 0][xrow + 32] = yh1.x;
        xt[xf4 + 1][xrow] = yh0.y;  xt[xf4 + 1][xrow + 32] = yh1.y;
        xt[xf4 + 2][xrow] = yh0.z;  xt[xf4 + 2][xrow + 32] = yh1.z;
        xt[xf4 + 3][xrow] = yh0.w;  xt[xf4 + 3][xrow + 32] = yh1.w;
        const int r0 = 8 * w;
#pragma unroll
        for (int i = 0; i < 4; ++i) {
            fireb[r0 + 2 * i][lane]     = f2bf(fireB[i].x);
            fireb[r0 + 2 * i + 1][lane] = f2bf(fireB[i].y);
        }
#pragma unroll
        for (int i = 0; i < 4; ++i) {
            float sx = fireB[i].x, sy = fireB[i].y;
#pragma unroll
            for (int d = 1; d < 64; d <<= 1) {
                sx += __shfl_xor(sx, d);
                sy += __shfl_xor(sy, d);
            }
            if (lane == 0) {
                rinv[r0 + 2 * i]     = 1.0f / sx;
                rinv[r0 + 2 * i + 1] = 1.0f / sy;
            }
        }
    }
    __syncthreads();   // B3: xt/fireb/rinv (T1) ready

    // ======================= phase C: stage 2 (T1) ==========================
    bf16x8 wfB[2][2];
#pragma unroll
    for (int mm = 0; mm < 2; ++mm) {
        const int myrow = 32 * g + 16 * mm + m_in;
        wfB[mm][0] = *(const bf16x8*)((const char*)&fireb[myrow][0] + q16);
        wfB[mm][1] = *(const bf16x8*)((const char*)&fireb[myrow][32] + q16);
    }
    f32x4 accB[2];
    accB[0] = z4;  accB[1] = z4;

#pragma unroll 2
    for (int i = 0; i < 32; ++i) {
        const int fe = 2 * i, fo = 2 * i + 1;
        bf16x8 ce0 = pe0, ce1 = pe1, co0 = po0, co1 = po1;
        const int se = (fe + 2 <= 64) ? fe + 2 : 64;
        const int so = (fo + 2 <= 64) ? fo + 2 : 64;
        pe0 = wpb[(2 * se) * 64];  pe1 = wpb[(2 * se + 1) * 64];
        po0 = wpb[(2 * so) * 64];  po1 = wpb[(2 * so + 1) * 64];
#pragma unroll
        for (int mm = 0; mm < 2; ++mm) {
            f32x4 U = __builtin_amdgcn_mfma_f32_16x16x32_bf16(wfB[mm][0], ce0, z4, 0, 0, 0);
            U = __builtin_amdgcn_mfma_f32_16x16x32_bf16(wfB[mm][1], ce1, U, 0, 0, 0);
            f32x4 xv = *(const f32x4*)&xt[fe][32 * g + 16 * mm + quad * 4];
#pragma unroll
            for (int reg = 0; reg < 4; ++reg)
                accB[mm][reg] = __builtin_fmaf(xv[reg], U[reg], accB[mm][reg]);
        }
#pragma unroll
        for (int mm = 0; mm < 2; ++mm) {
            f32x4 U = __builtin_amdgcn_mfma_f32_16x16x32_bf16(wfB[mm][0], co0, z4, 0, 0, 0);
            U = __builtin_amdgcn_mfma_f32_16x16x32_bf16(wfB[mm][1], co1, U, 0, 0, 0);
            f32x4 xv = *(const f32x4*)&xt[fo][32 * g + 16 * mm + quad * 4];
#pragma unroll
            for (int reg = 0; reg < 4; ++reg)
                accB[mm][reg] = __builtin_fmaf(xv[reg], U[reg], accB[mm][reg]);
        }
    }
#pragma unroll
    for (int mm = 0; mm < 2; ++mm) {
        f32x4 U = __builtin_amdgcn_mfma_f32_16x16x32_bf16(wfB[mm][0], pe0, z4, 0, 0, 0);
        U = __builtin_amdgcn_mfma_f32_16x16x32_bf16(wfB[mm][1], pe1, U, 0, 0, 0);
#pragma unroll
        for (int reg = 0; reg < 4; ++reg)
            accB[mm][reg] += U[reg];
    }
#pragma unroll
    for (int mm = 0; mm < 2; ++mm) {
        f32x4 rv = *(const f32x4*)&rinv[32 * g + 16 * mm + quad * 4];
#pragma unroll
        for (int reg = 0; reg < 4; ++reg) {
            const int row = b0 + 64 + 32 * g + 16 * mm + quad * 4 + reg;
            out[(size_t)row * 64 + nt * 16 + m_in] = accB[mm][reg] * rv[reg];
        }
    }
}

extern "C" void kernel_launch(void* const* d_in, const int* in_sizes, int n_in,
                              void* d_out, int out_size, void* d_ws, size_t ws_size,
                              hipStream_t stream) {
    const float* X    = (const float*)d_in[0];
    const float* tt   = (const float*)d_in[1];
    const float* mean = (const float*)d_in[2];
    const float* std_ = (const float*)d_in[3];
    const float* W    = (const float*)d_in[4];
    float* out = (float*)d_out;

    // workspace: prm (float4 x 4096 = 64 KiB) | Wpk (bf16 x 65*512*8 = 520 KiB)
    float* prm = (float*)d_ws;
    unsigned short* Wpk = (unsigned short*)((char*)d_ws + 65536);

    fq_prep<<<146, 256, 0, stream>>>(tt, mean, std_, W, prm, Wpk);

    // 256 blocks x 512 thr, 128 rows/block (2 tiles), 1 block/CU
    fq_main<<<256, 512, 0, stream>>>(X, (const float4*)prm,
                                     (const bf16x8*)Wpk, out);
}

// Round 10
// 105.984 us; speedup vs baseline: 1.0480x; 1.0480x over previous
//
#include <hip/hip_runtime.h>
#include <hip/hip_bf16.h>

#define F 64
#define R 64
#define O 64
#define BLOCK_B 64   // batch rows per block (512 threads, 8 waves)

typedef short bf16x8 __attribute__((ext_vector_type(8)));
typedef float f32x4 __attribute__((ext_vector_type(4)));
typedef float f32x2 __attribute__((ext_vector_type(2)));

static __device__ __forceinline__ unsigned short f2bf(float f) {
    unsigned u = __builtin_bit_cast(unsigned, f);
    unsigned r = (u + 0x7fffu + ((u >> 16) & 1u)) >> 16;
    return (unsigned short)r;
}

// Guaranteed packed-FP32 (VOP3P, gfx90a+): one instruction per 2 elements.
static __device__ __forceinline__ f32x2 pk_mul(f32x2 a, f32x2 b) {
    f32x2 d;
    asm("v_pk_mul_f32 %0, %1, %2" : "=v"(d) : "v"(a), "v"(b));
    return d;
}
static __device__ __forceinline__ f32x2 pk_fma(f32x2 a, f32x2 b, f32x2 c) {
    f32x2 d;
    asm("v_pk_fma_f32 %0, %1, %2, %3" : "=v"(d) : "v"(a), "v"(b), "v"(c));
    return d;
}

// ---------------------------------------------------------------------------
// Prep kernel (flat, 162 blocks x 256).
//   threads [0, 33280): pack W -> Wpk (bf16, MFMA B-frag order) — proven.
//   threads [33280, 37376): prm[u] = {s, mn*s, t, c}, u = f*64 + r
//   threads [37376, 41472): pB[u]  = {t, t, c, c}  (pair-splats for pk ops)
// ---------------------------------------------------------------------------
__global__ __launch_bounds__(256) void fq_prep(
        const float* __restrict__ tt, const float* __restrict__ mean,
        const float* __restrict__ std_, const float* __restrict__ W,
        float* __restrict__ prm, float* __restrict__ pB,
        unsigned short* __restrict__ Wpk)
{
    const int tg = blockIdx.x * 256 + threadIdx.x;
    if (tg < 65 * 512) {
        const int f    = tg >> 9;
        const int u8   = tg & 511;
        const int lane = u8 & 63;
        const int kk   = (u8 >> 6) & 1;
        const int nt   = u8 >> 7;
        const int o    = nt * 16 + (lane & 15);
        const int rb   = ((lane >> 4) << 3) + kk * 32;
        const float* src = W + o * 4160 + f * 64 + rb;
        unsigned short v[8];
#pragma unroll
        for (int j = 0; j < 8; ++j) v[j] = f2bf(src[j]);
        const int dst = ((nt * 65 + f) * 2 + kk) * 64 + lane;
        *(bf16x8*)(Wpk + (size_t)dst * 8) = *(bf16x8*)v;
    } else if (tg < 65 * 512 + 4096) {
        const int u = tg - 65 * 512;
        float sd = std_[u];
        float mn = mean[u];
        float th = tanhf(tt[u]);
        float s  = 1.2011224087864498f / sd;  // sqrt(log2(e)) / std
        float4 p;
        p.x = s;
        p.y = mn * s;
        p.z = th;
        p.w = 0.5f * (1.0f - th);
        ((float4*)prm)[u] = p;
    } else if (tg < 65 * 512 + 8192) {
        const int u = tg - (65 * 512 + 4096);
        float th = tanhf(tt[u]);
        float c  = 0.5f * (1.0f - th);
        float4 q;
        q.x = th;  q.y = th;
        q.z = c;   q.w = c;
        ((float4*)pB)[u] = q;
    }
}

// ---------------------------------------------------------------------------
// Main fused kernel, V10: round-0 structure (best measured, 45.3 us) with ONE
// change — stage-1 inner math forced to packed FP32 via inline-asm
// v_pk_mul_f32 / v_pk_fma_f32, with {t,t}/{c,c} pair-splats streamed from the
// pB prep table (natural b128-load pairs; no per-f splat movs). Per element-
// pair: 2 fma + 3 pk + 2 exp2 vs 8 VALU + 2 exp2 if clang scalarized f32x2.
// Rationale: VALU-busy cycles (~46K/SIMD) is the conserved dominant pipe
// across 7 falsified structural theories -> reduce VALU ops, nothing else.
// ---------------------------------------------------------------------------
__global__ __launch_bounds__(512, 2) void fq_main(
        const float* __restrict__ X,
        const float4* __restrict__ prm,
        const float4* __restrict__ pB,
        const bf16x8* __restrict__ Wp,
        float* __restrict__ out)
{
    __shared__ __align__(16) float xt[64][68];              // [f][row]
    __shared__ __align__(16) unsigned short fireb[64][72];  // [row][r] bf16
    __shared__ __align__(16) float rinv[BLOCK_B];

    const int t    = threadIdx.x;
    const int lane = t & 63;
    const int w    = __builtin_amdgcn_readfirstlane(t >> 6);  // wave 0..7
    const int b0   = blockIdx.x * BLOCK_B;
    const int nt   = w >> 1;
    const int g    = w & 1;

    // ---- issue X loads + first W prefetch pair early (in flight thru st.1) -
    const int xrow = t >> 4;          // 0..31
    const int xf4  = (t & 15) * 4;
    float4 xh0 = *(const float4*)(X + (size_t)(b0 + xrow) * 64 + xf4);
    float4 xh1 = *(const float4*)(X + (size_t)(b0 + xrow + 32) * 64 + xf4);

    const bf16x8* wpb = Wp + (size_t)(nt * 130) * 64 + lane;
    bf16x8 pe0 = wpb[0 * 64],  pe1 = wpb[1 * 64];     // f = 0
    bf16x8 po0 = wpb[2 * 64],  po1 = wpb[3 * 64];     // f = 1

    // ---- stage 1: firing strengths, rows 8w..8w+7, lane = r ----------------
    {
        f32x2 fire2[4];
#pragma unroll
        for (int i = 0; i < 4; ++i) fire2[i] = (f32x2){1.f, 1.f};
        const float* Xw = X + (size_t)(b0 + 8 * w) * 64;
        float4 p  = prm[lane];         // f = 0
        float4 pb = pB[lane];
#pragma unroll 2
        for (int f = 0; f < F; ++f) {
            const int pf = (f + 1 < 64) ? f + 1 : 63;
            float4 pn  = prm[pf * 64 + lane];     // distance-1 prefetch
            float4 pbn = pB[pf * 64 + lane];
            f32x2 t2;  t2.x = pb.x;  t2.y = pb.y;   // consecutive regs of b128
            f32x2 c2;  c2.x = pb.z;  c2.y = pb.w;
#pragma unroll
            for (int i = 0; i < 4; ++i) {
                float x0 = Xw[(2 * i) * 64 + f];      // wave-uniform -> s_load
                float x1 = Xw[(2 * i + 1) * 64 + f];
                f32x2 z;
                z.x = __builtin_fmaf(x0, p.x, -p.y);
                z.y = __builtin_fmaf(x1, p.x, -p.y);
                f32x2 q = pk_mul(z, z);
                f32x2 g2;
                g2.x = __builtin_amdgcn_exp2f(-q.x);  // neg folds to src mod
                g2.y = __builtin_amdgcn_exp2f(-q.y);
                fire2[i] = pk_mul(fire2[i], pk_fma(g2, t2, c2));
            }
            p = pn;  pb = pbn;
        }
        // write X slab (transposed) + raw-fire bf16 rows
        xt[xf4 + 0][xrow] = xh0.x;  xt[xf4 + 0][xrow + 32] = xh1.x;
        xt[xf4 + 1][xrow] = xh0.y;  xt[xf4 + 1][xrow + 32] = xh1.y;
        xt[xf4 + 2][xrow] = xh0.z;  xt[xf4 + 2][xrow + 32] = xh1.z;
        xt[xf4 + 3][xrow] = xh0.w;  xt[xf4 + 3][xrow + 32] = xh1.w;
        const int r0 = 8 * w;
#pragma unroll
        for (int i = 0; i < 4; ++i) {
            fireb[r0 + 2 * i][lane]     = f2bf(fire2[i].x);
            fireb[r0 + 2 * i + 1][lane] = f2bf(fire2[i].y);
        }
        // in-wave butterfly row sums -> rinv (no extra barrier/phase)
#pragma unroll
        for (int i = 0; i < 4; ++i) {
            float sx = fire2[i].x, sy = fire2[i].y;
#pragma unroll
            for (int d = 1; d < 64; d <<= 1) {
                sx += __shfl_xor(sx, d);
                sy += __shfl_xor(sy, d);
            }
            if (lane == 0) {
                rinv[r0 + 2 * i]     = 1.0f / sx;
                rinv[r0 + 2 * i + 1] = 1.0f / sy;
            }
        }
    }
    __syncthreads();   // the ONE barrier

    // ---- stage 2: 2 row-tiles per wave, dist-2 W prefetch ------------------
    const int m_in = lane & 15;
    const int quad = lane >> 4;
    const int q16  = quad * 16;   // byte offset of quad's 8-bf16 chunk

    bf16x8 wfrag[2][2];   // [mm][kk] — direct reads, raw (unnormalized) fire
#pragma unroll
    for (int mm = 0; mm < 2; ++mm) {
        const int myrow = 32 * g + 16 * mm + m_in;
        wfrag[mm][0] = *(const bf16x8*)((const char*)&fireb[myrow][0] + q16);
        wfrag[mm][1] = *(const bf16x8*)((const char*)&fireb[myrow][32] + q16);
    }

    f32x4 acc[2];
    acc[0] = (f32x4){0.f, 0.f, 0.f, 0.f};
    acc[1] = (f32x4){0.f, 0.f, 0.f, 0.f};
    const f32x4 z4 = (f32x4){0.f, 0.f, 0.f, 0.f};

#pragma unroll 2
    for (int i = 0; i < 32; ++i) {
        const int fe = 2 * i, fo = 2 * i + 1;
        bf16x8 ce0 = pe0, ce1 = pe1, co0 = po0, co1 = po1;
        const int se = (fe + 2 <= 64) ? fe + 2 : 64;   // clamp to bias slab
        const int so = (fo + 2 <= 64) ? fo + 2 : 64;
        pe0 = wpb[(2 * se) * 64];  pe1 = wpb[(2 * se + 1) * 64];
        po0 = wpb[(2 * so) * 64];  po1 = wpb[(2 * so + 1) * 64];
#pragma unroll
        for (int mm = 0; mm < 2; ++mm) {
            f32x4 U = __builtin_amdgcn_mfma_f32_16x16x32_bf16(wfrag[mm][0], ce0, z4, 0, 0, 0);
            U = __builtin_amdgcn_mfma_f32_16x16x32_bf16(wfrag[mm][1], ce1, U, 0, 0, 0);
            f32x4 xv = *(const f32x4*)&xt[fe][32 * g + 16 * mm + quad * 4];
#pragma unroll
            for (int reg = 0; reg < 4; ++reg)
                acc[mm][reg] = __builtin_fmaf(xv[reg], U[reg], acc[mm][reg]);
        }
#pragma unroll
        for (int mm = 0; mm < 2; ++mm) {
            f32x4 U = __builtin_amdgcn_mfma_f32_16x16x32_bf16(wfrag[mm][0], co0, z4, 0, 0, 0);
            U = __builtin_amdgcn_mfma_f32_16x16x32_bf16(wfrag[mm][1], co1, U, 0, 0, 0);
            f32x4 xv = *(const f32x4*)&xt[fo][32 * g + 16 * mm + quad * 4];
#pragma unroll
            for (int reg = 0; reg < 4; ++reg)
                acc[mm][reg] = __builtin_fmaf(xv[reg], U[reg], acc[mm][reg]);
        }
    }

    // bias slab (x = 1): pair resident in pe0/pe1 from the exit prefetch
#pragma unroll
    for (int mm = 0; mm < 2; ++mm) {
        f32x4 U = __builtin_amdgcn_mfma_f32_16x16x32_bf16(wfrag[mm][0], pe0, z4, 0, 0, 0);
        U = __builtin_amdgcn_mfma_f32_16x16x32_bf16(wfrag[mm][1], pe1, U, 0, 0, 0);
#pragma unroll
        for (int reg = 0; reg < 4; ++reg)
            acc[mm][reg] += U[reg];
    }

    // epilogue: out = acc * rinv[row];  C/D: col = lane&15, row = quad*4+reg
#pragma unroll
    for (int mm = 0; mm < 2; ++mm) {
        f32x4 rv = *(const f32x4*)&rinv[32 * g + 16 * mm + quad * 4];
#pragma unroll
        for (int reg = 0; reg < 4; ++reg) {
            const int row = b0 + 32 * g + 16 * mm + quad * 4 + reg;
            out[(size_t)row * 64 + nt * 16 + m_in] = acc[mm][reg] * rv[reg];
        }
    }
}

extern "C" void kernel_launch(void* const* d_in, const int* in_sizes, int n_in,
                              void* d_out, int out_size, void* d_ws, size_t ws_size,
                              hipStream_t stream) {
    const float* X    = (const float*)d_in[0];
    const float* tt   = (const float*)d_in[1];
    const float* mean = (const float*)d_in[2];
    const float* std_ = (const float*)d_in[3];
    const float* W    = (const float*)d_in[4];
    float* out = (float*)d_out;

    // workspace: prm (64 KiB) | pB (64 KiB) | Wpk (520 KiB)
    float* prm = (float*)d_ws;
    float* pB  = (float*)((char*)d_ws + 65536);
    unsigned short* Wpk = (unsigned short*)((char*)d_ws + 131072);

    fq_prep<<<162, 256, 0, stream>>>(tt, mean, std_, W, prm, pB, Wpk);

    const int nblocks = 32768 / BLOCK_B;  // 512 blocks x 512 thr = 4096 waves
    fq_main<<<nblocks, 512, 0, stream>>>(X, (const float4*)prm,
                                         (const float4*)pB,
                                         (const bf16x8*)Wpk, out);
}